// Round 6
// baseline (253.697 us; speedup 1.0000x reference)
//
#include <hip/hip_runtime.h>

// B=2, S=2048, H=1024, NUM_HEAD=16, HEAD=64
#define BATCH 2
#define S_LEN 2048
#define HDIM  1024
#define NHEAD 16
#define HD    64
#define NEGBIAS -1e10f
#define LOG2E 1.44269504088896f

typedef __attribute__((ext_vector_type(8))) _Float16 half8;  // 8 f16 in 4 VGPRs
typedef __attribute__((ext_vector_type(4))) _Float16 half4;  // 4 f16 in 2 VGPRs
typedef __attribute__((ext_vector_type(4))) float   f32x4;   // MFMA C/D frag
// cvt_pkrtz plumbing uses __fp16 vectors (the builtin's native type)
typedef __attribute__((ext_vector_type(2))) __fp16 fp16x2;
typedef __attribute__((ext_vector_type(4))) __fp16 fp16x4;
typedef __attribute__((ext_vector_type(8))) __fp16 fp16x8;

__device__ __forceinline__ float max3f(float a, float b, float c) {
    return fmaxf(fmaxf(a, b), c);        // clang fuses to v_max3_f32
}

// async global->LDS, 16B per lane (wave writes 1024B linearly from lds base)
__device__ __forceinline__ void gload16(const float* g, float* l) {
    __builtin_amdgcn_global_load_lds(
        (const __attribute__((address_space(1))) unsigned int*)g,
        (__attribute__((address_space(3))) unsigned int*)l, 16, 0, 0);
}

// packed fp32x8 -> f16x8 (4 cvt_pkrtz), inputs as f32x4
#define PK8V(dst, lo, hi)                                                     \
    {                                                                         \
        fp16x2 p0 = __builtin_amdgcn_cvt_pkrtz((lo)[0], (lo)[1]);             \
        fp16x2 p1 = __builtin_amdgcn_cvt_pkrtz((lo)[2], (lo)[3]);             \
        fp16x2 p2 = __builtin_amdgcn_cvt_pkrtz((hi)[0], (hi)[1]);             \
        fp16x2 p3 = __builtin_amdgcn_cvt_pkrtz((hi)[2], (hi)[3]);             \
        fp16x4 l4 = __builtin_shufflevector(p0, p1, 0, 1, 2, 3);              \
        fp16x4 h4 = __builtin_shufflevector(p2, p3, 0, 1, 2, 3);              \
        fp16x8 v8 = __builtin_shufflevector(l4, h4, 0, 1, 2, 3, 4, 5, 6, 7);  \
        dst = __builtin_bit_cast(half8, v8);                                  \
    }

// ---------------------------------------------------------------------------
// Fused projection GEMM v3.  R5 post-mortem: reg-staging phase convoy is the
// bottleneck (deeper reg prefetch = no change; all counters ~12%).  R6:
//  * global_load_lds DIRECT fp32 staging (no reg round-trip, no ds_write,
//    no stage VALU) -- the m93->m97 +69% ladder step.
//  * double-buffered LDS (fp32 [2][128][32] per operand, 64 KB), ONE barrier
//    per BK=32: issue next-buf loads -> compute cur -> barrier (vmcnt drain
//    hides under MFMA).  T3 minimum-2-phase recipe.
//  * rule-21 swizzle: linear LDS dest + inverse-swizzled global SOURCE
//    (col16 ^= row&7) + same XOR on read, folded into 2 per-lane base addrs
//    + mt*2048 immediates (zero per-access VALU -- R2 lesson).
//  * fp32->f16 conversion at fragment-read time (PK8V).
//  * XCD-ownership 1D grid kept (FETCH 202->74 MB in R5).
// z==0 (Q) output PRE-SCALED by log2(e) so attention can use exp2 directly.
// ---------------------------------------------------------------------------
__global__ __launch_bounds__(256) void proj_gemm_f16(
    const float* __restrict__ Xq, const float* __restrict__ Wq, const float* __restrict__ bq,
    const float* __restrict__ Xk, const float* __restrict__ Wk, const float* __restrict__ bk,
    const float* __restrict__ Xv, const float* __restrict__ Wv, const float* __restrict__ bv,
    _Float16* __restrict__ Qb, _Float16* __restrict__ Kb, _Float16* __restrict__ Vtb)
{
    // XCD-aware decomposition (hw: XCD = bid & 7): XCD x owns m-tiles
    // {4x..4x+3} for all (n,z) -> concurrent blocks share an L2 X panel.
    const int l  = blockIdx.x;           // 0..767
    const int x  = l & 7;                // XCD
    const int j  = l >> 3;               // 0..95
    const int mt_ = x * 4 + (j & 3);     // 0..31
    const int nt_ = (j >> 2) & 7;        // 0..7
    const int z   = j >> 5;              // 0..2

    const float* X    = (z == 0) ? Xq : (z == 1) ? Xk : Xv;
    const float* W    = (z == 0) ? Wq : (z == 1) ? Wk : Wv;
    const float* bias = (z == 0) ? bq : (z == 1) ? bk : bv;
    _Float16* Y       = (z == 0) ? Qb : (z == 1) ? Kb : Vtb;

    const int n0 = nt_ * 128;
    const int m0 = mt_ * 128;

    // fp32 tiles, LINEAR [128][32] (no pad -- global_load_lds dest), dbuf
    __shared__ __align__(16) float As[2][128 * 32];     // 2 x 16 KB
    __shared__ __align__(16) float Bs[2][128 * 32];     // 2 x 16 KB

    const int t    = threadIdx.x;
    const int w    = t >> 6;
    const int lane = t & 63;
    const int quad = lane >> 4;
    const int lc   = lane & 15;
    const int wm   = (w >> 1) * 64;
    const int wn   = (w & 1) * 64;

    const f32x4 fzero = {0.f, 0.f, 0.f, 0.f};
    f32x4 acc[4][4];
#pragma unroll
    for (int i = 0; i < 4; i++)
#pragma unroll
        for (int j2 = 0; j2 < 4; j2++) acc[i][j2] = fzero;

    // --- staging geometry: wave w stages chunks {w*4..w*4+3} of each tile.
    // chunk c = rows (w*4+c)*8 .. +7.  lane i: row += i>>3, col16 = i&7,
    // SOURCE-swizzled: global col16 = (i&7) ^ (i>>3)  (involution w/ read XOR)
    const int lr  = lane >> 3;                 // row within 8-row chunk
    const int lcx = (lane & 7) ^ lr;           // inverse-swizzled col16
    const float* gA = X + (size_t)(m0 + w * 32 + lr) * HDIM + lcx * 4;
    const float* gB = W + (size_t)(n0 + w * 32 + lr) * HDIM + lcx * 4;
    const int ach = w * 1024;                  // wave's chunk base (floats)

#define PROJ_STAGE(BUF, K0)                                                   \
    {                                                                         \
        _Pragma("unroll")                                                     \
        for (int c = 0; c < 4; c++) {                                         \
            gload16(gA + (K0) + c * 8192, &As[BUF][ach + c * 256]);           \
            gload16(gB + (K0) + c * 8192, &Bs[BUF][ach + c * 256]);           \
        }                                                                     \
    }

    // --- fragment-read geometry (swizzled): row = wm+mt*16+lc, row&7 = lc&7.
    // frag floats k=quad*8..+7 live at col16 (quad*2+j)^(lc&7), j=0,1.
    const int xr   = lc & 7;
    const int arow = (wm + lc) * 32;           // float index of row base
    const int brow = (wn + lc) * 32;
    const int ac0  = ((quad * 2)     ^ xr) * 4;
    const int ac1  = ((quad * 2 + 1) ^ xr) * 4;

#define PROJ_COMPUTE(BUF)                                                     \
    {                                                                         \
        half8 af[4], bf[4];                                                   \
        _Pragma("unroll")                                                     \
        for (int mt = 0; mt < 4; mt++) {                                      \
            f32x4 lo = *(const f32x4*)&As[BUF][arow + mt * 512 + ac0];        \
            f32x4 hi = *(const f32x4*)&As[BUF][arow + mt * 512 + ac1];        \
            PK8V(af[mt], lo, hi)                                              \
        }                                                                     \
        _Pragma("unroll")                                                     \
        for (int nt = 0; nt < 4; nt++) {                                      \
            f32x4 lo = *(const f32x4*)&Bs[BUF][brow + nt * 512 + ac0];        \
            f32x4 hi = *(const f32x4*)&Bs[BUF][brow + nt * 512 + ac1];        \
            PK8V(bf[nt], lo, hi)                                              \
        }                                                                     \
        _Pragma("unroll")                                                     \
        for (int mt = 0; mt < 4; mt++)                                        \
            _Pragma("unroll")                                                 \
            for (int nt = 0; nt < 4; nt++)                                    \
                acc[mt][nt] = __builtin_amdgcn_mfma_f32_16x16x32_f16(         \
                    af[mt], bf[nt], acc[mt][nt], 0, 0, 0);                    \
    }

    PROJ_STAGE(0, 0)
    __syncthreads();                    // prologue drain: buf0 ready

    for (int k0 = 0; k0 < HDIM; k0 += 64) {
        if (k0 + 32 < HDIM) PROJ_STAGE(1, k0 + 32)   // issue early
        PROJ_COMPUTE(0)                               // hide drain under MFMA
        __syncthreads();                              // buf1 ready, buf0 free
        if (k0 + 64 < HDIM) PROJ_STAGE(0, k0 + 64)
        PROJ_COMPUTE(1)
        __syncthreads();
    }

#pragma unroll
    for (int nt = 0; nt < 4; nt++) {
        const int n = n0 + wn + nt * 16 + lc;          // h*64 + d
        const float bv_ = bias[n];
        const int h = n >> 6, d = n & 63;
#pragma unroll
        for (int mt = 0; mt < 4; mt++) {
#pragma unroll
            for (int r = 0; r < 4; r++) {
                const int m = m0 + wm + mt * 16 + quad * 4 + r;   // b*S + s
                const int b = m >> 11, s = m & (S_LEN - 1);
                const int bh = b * NHEAD + h;
                float y = acc[mt][nt][r] + bv_;
                if (z == 0) y *= LOG2E;                 // exp2-fold for attn
                _Float16 val = (_Float16)y;
                if (z == 2)
                    Y[((size_t)bh * HD + d) * S_LEN + s] = val;          // V^T
                else
                    Y[((size_t)bh * S_LEN + s) * HD + d] = val;          // Q,K
            }
        }
    }
}

// ---------------------------------------------------------------------------
// Flash attention v4 (unchanged from R4).  Padded [64][72] LDS (immediate
// offsets), bias folded into MFMA C-init, exp2 log2-domain softmax, v_max3
// trees, cvt_pkrtz packed P, defer-max, XCD-aware block swizzle.
// S^T = K.Q^T, O^T = V^T.P^T, 128-row tiles, 4 waves, 2 q-groups/wave.
// ---------------------------------------------------------------------------
__global__ __launch_bounds__(256) void flash_attn_mfma(
    const _Float16* __restrict__ Qb, const _Float16* __restrict__ Kb,
    const _Float16* __restrict__ Vtb, const int* __restrict__ mask,
    float* __restrict__ out)
{
    const int bid = blockIdx.x;                  // 0..511
    const int swz = (bid & 7) * 64 + (bid >> 3);
    const int qt = swz & 15;                     // 16 q-tiles of 128 rows
    const int bh = swz >> 4;                     // 0..31
    const int b  = bh >> 4;
    const int h  = bh & (NHEAD - 1);

    __shared__ __align__(16) _Float16 Ks [64][72];      // [key][d]
    __shared__ __align__(16) _Float16 Vts[64][72];      // [d][key]
    __shared__ __align__(16) _Float16 Ps [4][32][72];   // per-wave P, [q][key]
    __shared__ float biasS[64];                         // mask bias per key

    const int t    = threadIdx.x;
    const int w    = t >> 6;
    const int lane = t & 63;
    const int quad = lane >> 4;
    const int lc   = lane & 15;

    const _Float16* Kbase = Kb  + (size_t)bh * S_LEN * HD;
    const _Float16* Vbase = Vtb + (size_t)bh * HD * S_LEN;
    const int* mbase = mask + b * S_LEN;

    // Q B-frags: qg in {0,1}, q-row = qt*128 + w*32 + qg*16 + lc
    half8 qf[2][2];
#pragma unroll
    for (int qg = 0; qg < 2; qg++) {
        const int qrow = qt * 128 + w * 32 + qg * 16 + lc;
#pragma unroll
        for (int s = 0; s < 2; s++)
            qf[qg][s] = *(const half8*)(Qb + ((size_t)bh * S_LEN + qrow) * HD
                                        + s * 32 + quad * 8);
    }

    f32x4 o[2][4];                      // O^T per qg: d = nt*16+quad*4+r, q = lc
    const f32x4 fzero = {0.f, 0.f, 0.f, 0.f};
#pragma unroll
    for (int qg = 0; qg < 2; qg++)
#pragma unroll
        for (int nt = 0; nt < 4; nt++) o[qg][nt] = fzero;
    float mrun[2] = {-3.0e38f, -3.0e38f};
    float lrun[2] = {0.f, 0.f};

    // staging geometry: chunk c = t + 256*i -> row c>>3, col (c&7)*8
    const int rr0 = t >> 3,          cc0 = (t & 7) * 8;
    const int rr1 = (t + 256) >> 3;                       // rows 32..63

    half8 kpre[2], vpre[2];
    int   mpre;
#define ATTN_ISSUE(KT)                                                        \
    {                                                                         \
        kpre[0] = *(const half8*)(Kbase + (size_t)((KT) + rr0) * HD + cc0);   \
        kpre[1] = *(const half8*)(Kbase + (size_t)((KT) + rr1) * HD + cc0);   \
        vpre[0] = *(const half8*)(Vbase + (size_t)rr0 * S_LEN + (KT) + cc0);  \
        vpre[1] = *(const half8*)(Vbase + (size_t)rr1 * S_LEN + (KT) + cc0);  \
        mpre    = mbase[(KT) + (t & 63)];                                     \
    }

    ATTN_ISSUE(0)

    for (int kt = 0; kt < S_LEN; kt += 64) {
        if (kt) __syncthreads();        // prev iter done reading LDS
        *(half8*)&Ks [rr0][cc0] = kpre[0];
        *(half8*)&Ks [rr1][cc0] = kpre[1];
        *(half8*)&Vts[rr0][cc0] = vpre[0];
        *(half8*)&Vts[rr1][cc0] = vpre[1];
        if (t < 64) biasS[t] = mpre ? 0.f : NEGBIAS;
        __syncthreads();

        if (kt + 64 < S_LEN) ATTN_ISSUE(kt + 64)   // overlap with compute

        // S^T = K.Q^T, mask bias pre-loaded into the MFMA C operand.
        f32x4 scf[2][4];
#pragma unroll
        for (int tt = 0; tt < 4; tt++) {
            float4 b4 = *(const float4*)&biasS[tt * 16 + quad * 4];
            f32x4 cini = {b4.x, b4.y, b4.z, b4.w};
            scf[0][tt] = cini;
            scf[1][tt] = cini;
        }
#pragma unroll
        for (int s = 0; s < 2; s++) {
#pragma unroll
            for (int tt = 0; tt < 4; tt++) {
                half8 kf = *(const half8*)&Ks[tt * 16 + lc][s * 32 + quad * 8];
                scf[0][tt] = __builtin_amdgcn_mfma_f32_16x16x32_f16(kf, qf[0][s], scf[0][tt], 0, 0, 0);
                scf[1][tt] = __builtin_amdgcn_mfma_f32_16x16x32_f16(kf, qf[1][s], scf[1][tt], 0, 0, 0);
            }
        }

        // per-lane online softmax, one q-row per (qg, lc), log2 domain
#pragma unroll
        for (int qg = 0; qg < 2; qg++) {
            const f32x4 a0 = scf[qg][0], a1 = scf[qg][1],
                        a2 = scf[qg][2], a3 = scf[qg][3];
            float m0 = max3f(a0[0], a0[1], a0[2]);
            float m1 = max3f(a0[3], a1[0], a1[1]);
            float m2 = max3f(a1[2], a1[3], a2[0]);
            float m3 = max3f(a2[1], a2[2], a2[3]);
            float m4 = max3f(a3[0], a3[1], a3[2]);
            float mx = fmaxf(max3f(m0, m1, m2), max3f(m3, m4, a3[3]));
            mx = fmaxf(mx, __shfl_xor(mx, 16));
            mx = fmaxf(mx, __shfl_xor(mx, 32));

            // defer-max (T13): skip o-rescale unless max grew past threshold.
            if (!__all(mx <= mrun[qg] + 8.f)) {
                float mn = fmaxf(mrun[qg], mx);
                float al = __builtin_amdgcn_exp2f(mrun[qg] - mn);
                lrun[qg] *= al;
#pragma unroll
                for (int nt = 0; nt < 4; nt++) {
                    o[qg][nt][0] *= al; o[qg][nt][1] *= al;
                    o[qg][nt][2] *= al; o[qg][nt][3] *= al;
                }
                mrun[qg] = mn;
            }

            const float mr = mrun[qg];
            float ps[4][4];
#pragma unroll
            for (int tt = 0; tt < 4; tt++)
#pragma unroll
                for (int r = 0; r < 4; r++) {
                    float p = __builtin_amdgcn_exp2f(scf[qg][tt][r] - mr);
                    ps[tt][r] = p;
                }
            // pairwise sum tree
            float s0 = (ps[0][0] + ps[0][1]) + (ps[0][2] + ps[0][3]);
            float s1 = (ps[1][0] + ps[1][1]) + (ps[1][2] + ps[1][3]);
            float s2 = (ps[2][0] + ps[2][1]) + (ps[2][2] + ps[2][3]);
            float s3 = (ps[3][0] + ps[3][1]) + (ps[3][2] + ps[3][3]);
            float ls = (s0 + s1) + (s2 + s3);
            ls += __shfl_xor(ls, 16);
            ls += __shfl_xor(ls, 32);
            lrun[qg] += ls;

            // P rows (q-major): Ps[w][qg*16+lc][key], packed RTZ conversion
#pragma unroll
            for (int tt = 0; tt < 4; tt++) {
                fp16x2 p01 = __builtin_amdgcn_cvt_pkrtz(ps[tt][0], ps[tt][1]);
                fp16x2 p23 = __builtin_amdgcn_cvt_pkrtz(ps[tt][2], ps[tt][3]);
                fp16x4 pk4 = __builtin_shufflevector(p01, p23, 0, 1, 2, 3);
                *(half4*)&Ps[w][qg * 16 + lc][tt * 16 + quad * 4] =
                    __builtin_bit_cast(half4, pk4);
            }
        }

        // O^T += V^T.P^T : each vf read feeds both qg MFMAs
#pragma unroll
        for (int s = 0; s < 2; s++) {
            half8 pf0 = *(const half8*)&Ps[w][lc]     [s * 32 + quad * 8];
            half8 pf1 = *(const half8*)&Ps[w][16 + lc][s * 32 + quad * 8];
#pragma unroll
            for (int nt = 0; nt < 4; nt++) {
                half8 vf = *(const half8*)&Vts[nt * 16 + lc][s * 32 + quad * 8];
                o[0][nt] = __builtin_amdgcn_mfma_f32_16x16x32_f16(vf, pf0, o[0][nt], 0, 0, 0);
                o[1][nt] = __builtin_amdgcn_mfma_f32_16x16x32_f16(vf, pf1, o[1][nt], 0, 0, 0);
            }
        }
    }

    // epilogue: lane owns q-row per qg; contiguous float4 stores
#pragma unroll
    for (int qg = 0; qg < 2; qg++) {
        const int qrow = qt * 128 + w * 32 + qg * 16 + lc;
        const float inv = 1.f / lrun[qg];
        const size_t rowb = ((size_t)b * S_LEN + qrow) * HDIM + h * HD;
#pragma unroll
        for (int nt = 0; nt < 4; nt++) {
            float4 v;
            v.x = o[qg][nt][0] * inv; v.y = o[qg][nt][1] * inv;
            v.z = o[qg][nt][2] * inv; v.w = o[qg][nt][3] * inv;
            *(float4*)&out[rowb + nt * 16 + quad * 4] = v;
        }
    }
}

// ---------------------------------------------------------------------------
extern "C" void kernel_launch(void* const* d_in, const int* in_sizes, int n_in,
                              void* d_out, int out_size, void* d_ws, size_t ws_size,
                              hipStream_t stream) {
    const float* query = (const float*)d_in[0];
    const float* key   = (const float*)d_in[1];
    const float* value = (const float*)d_in[2];
    const int*   mask  = (const int*)  d_in[3];
    const float* Wq    = (const float*)d_in[4];
    const float* bq    = (const float*)d_in[5];
    const float* Wk    = (const float*)d_in[6];
    const float* bk    = (const float*)d_in[7];
    const float* Wv    = (const float*)d_in[8];
    const float* bv    = (const float*)d_in[9];
    float* out = (float*)d_out;

    const size_t nElem = (size_t)BATCH * S_LEN * HDIM;          // 4M
    if (ws_size < 3 * nElem * sizeof(_Float16)) return;         // 24 MB
    _Float16* Qb  = (_Float16*)d_ws;
    _Float16* Kb  = Qb + nElem;
    _Float16* Vtb = Kb + nElem;

    // 1D grid: 8 n-tiles x 32 m-tiles x 3 z = 768 blocks, XCD-decomposed
    proj_gemm_f16<<<768, 256, 0, stream>>>(query, Wq, bq, key, Wk, bk,
                                           value, Wv, bv, Qb, Kb, Vtb);

    flash_attn_mfma<<<BATCH * NHEAD * (S_LEN / 128), 256, 0, stream>>>(
        Qb, Kb, Vtb, mask, out);
}

// Round 7
// 241.777 us; speedup vs baseline: 1.0493x; 1.0493x over previous
//
#include <hip/hip_runtime.h>

// B=2, S=2048, H=1024, NUM_HEAD=16, HEAD=64
#define BATCH 2
#define S_LEN 2048
#define HDIM  1024
#define NHEAD 16
#define HD    64
#define NEGBIAS -1e10f
#define LOG2E 1.44269504088896f

typedef __attribute__((ext_vector_type(8))) _Float16 half8;  // 8 f16 in 4 VGPRs
typedef __attribute__((ext_vector_type(4))) _Float16 half4;  // 4 f16 in 2 VGPRs
typedef __attribute__((ext_vector_type(4))) float   f32x4;   // MFMA C/D frag
// cvt_pkrtz plumbing uses __fp16 vectors (the builtin's native type)
typedef __attribute__((ext_vector_type(2))) __fp16 fp16x2;
typedef __attribute__((ext_vector_type(4))) __fp16 fp16x4;
typedef __attribute__((ext_vector_type(8))) __fp16 fp16x8;

__device__ __forceinline__ float max3f(float a, float b, float c) {
    return fmaxf(fmaxf(a, b), c);        // clang fuses to v_max3_f32
}

__device__ __forceinline__ half8 pk8(float4 a, float4 b) {
    fp16x2 p0 = __builtin_amdgcn_cvt_pkrtz(a.x, a.y);
    fp16x2 p1 = __builtin_amdgcn_cvt_pkrtz(a.z, a.w);
    fp16x2 p2 = __builtin_amdgcn_cvt_pkrtz(b.x, b.y);
    fp16x2 p3 = __builtin_amdgcn_cvt_pkrtz(b.z, b.w);
    fp16x4 lo = __builtin_shufflevector(p0, p1, 0, 1, 2, 3);
    fp16x4 hi = __builtin_shufflevector(p2, p3, 0, 1, 2, 3);
    fp16x8 v8 = __builtin_shufflevector(lo, hi, 0, 1, 2, 3, 4, 5, 6, 7);
    return __builtin_bit_cast(half8, v8);
}

// ---------------------------------------------------------------------------
// fp32 -> f16 pre-conversion of X (3 x 4M elems) and W (3 x 1M elems).
// R4-R6 triangulated proj as CU-fill-rate bound (~9.4 TB/s L1<-L2 across all
// variants); halving input bytes is the only lever.  15M elems, 8/thread.
// ---------------------------------------------------------------------------
__global__ __launch_bounds__(256) void cvt_f32_f16(
    const float* __restrict__ Xq, const float* __restrict__ Xk, const float* __restrict__ Xv,
    const float* __restrict__ Wq, const float* __restrict__ Wk, const float* __restrict__ Wv,
    _Float16* __restrict__ Xfq, _Float16* __restrict__ Xfk, _Float16* __restrict__ Xfv,
    _Float16* __restrict__ Wfq, _Float16* __restrict__ Wfk, _Float16* __restrict__ Wfv)
{
    const int ub = blockIdx.x;           // 0..7679
    const float* src; _Float16* dst; int off;
    if      (ub < 2048) { src = Xq; dst = Xfq; off = ub; }
    else if (ub < 4096) { src = Xk; dst = Xfk; off = ub - 2048; }
    else if (ub < 6144) { src = Xv; dst = Xfv; off = ub - 4096; }
    else if (ub < 6656) { src = Wq; dst = Wfq; off = ub - 6144; }
    else if (ub < 7168) { src = Wk; dst = Wfk; off = ub - 6656; }
    else                { src = Wv; dst = Wfv; off = ub - 7168; }
    const int i = off * 2048 + threadIdx.x * 8;
    float4 a = *(const float4*)(src + i);
    float4 b = *(const float4*)(src + i + 4);
    *(half8*)(dst + i) = pk8(a, b);
}

// ---------------------------------------------------------------------------
// Projection GEMM, f16 inputs (primary path).  Y = X @ W^T + b.
// z=0,1 -> [B,NH,S,HD]; z=2 -> V transposed [B,NH,HD,S].
// 128x128 tile, BK=32, 2-deep register prefetch, XCD-ownership grid.
// f16 inputs halve the per-iter CU fill burst (16KB/block vs 32KB) so the
// ~1000-cyc prefetch window now covers it; staging is a pure half8 copy
// (zero cvt VALU in the loop).  z==0 (Q) PRE-SCALED by log2(e).
// ---------------------------------------------------------------------------
__global__ __launch_bounds__(256) void proj_gemm_f16in(
    const _Float16* __restrict__ Xfq, const _Float16* __restrict__ Wfq, const float* __restrict__ bq,
    const _Float16* __restrict__ Xfk, const _Float16* __restrict__ Wfk, const float* __restrict__ bk,
    const _Float16* __restrict__ Xfv, const _Float16* __restrict__ Wfv, const float* __restrict__ bv,
    _Float16* __restrict__ Qb, _Float16* __restrict__ Kb, _Float16* __restrict__ Vtb)
{
    // XCD-aware decomposition (hw: XCD = bid & 7): XCD x owns m-tiles
    // {4x..4x+3} for all (n,z) -> concurrent blocks share an L2 X panel.
    const int l  = blockIdx.x;           // 0..767
    const int x  = l & 7;                // XCD
    const int j  = l >> 3;               // 0..95
    const int mt_ = x * 4 + (j & 3);     // 0..31
    const int nt_ = (j >> 2) & 7;        // 0..7
    const int z   = j >> 5;              // 0..2

    const _Float16* X    = (z == 0) ? Xfq : (z == 1) ? Xfk : Xfv;
    const _Float16* W    = (z == 0) ? Wfq : (z == 1) ? Wfk : Wfv;
    const float*    bias = (z == 0) ? bq  : (z == 1) ? bk  : bv;
    _Float16*       Y    = (z == 0) ? Qb  : (z == 1) ? Kb  : Vtb;

    const int n0 = nt_ * 128;
    const int m0 = mt_ * 128;

    __shared__ __align__(16) _Float16 As[128][40];  // [m][k], pad 40
    __shared__ __align__(16) _Float16 Bs[128][40];  // [n][k]

    const int t    = threadIdx.x;
    const int w    = t >> 6;
    const int lane = t & 63;
    const int quad = lane >> 4;
    const int lc   = lane & 15;
    const int wm   = (w >> 1) * 64;
    const int wn   = (w & 1) * 64;

    const f32x4 fzero = {0.f, 0.f, 0.f, 0.f};
    f32x4 acc[4][4];
#pragma unroll
    for (int i = 0; i < 4; i++)
#pragma unroll
        for (int j2 = 0; j2 < 4; j2++) acc[i][j2] = fzero;

    // staging geometry: thread t covers rows srow & srow+64, elem col scol..+7
    const int srow = t >> 2;             // 0..63
    const int scol = (t & 3) * 8;        // {0,8,16,24}
    const _Float16* gX = X + (size_t)(m0 + srow) * HDIM + scol;
    const _Float16* gW = W + (size_t)(n0 + srow) * HDIM + scol;

    // two named prefetch register sets (static indexing only)
    half8 xa0[2], wa0[2], xa1[2], wa1[2];

#define PISS(K0, XA, WA)                                                      \
    {                                                                         \
        XA[0] = *(const half8*)(gX + (K0));                                   \
        XA[1] = *(const half8*)(gX + (K0) + (size_t)64 * HDIM);               \
        WA[0] = *(const half8*)(gW + (K0));                                   \
        WA[1] = *(const half8*)(gW + (K0) + (size_t)64 * HDIM);               \
    }

#define PSTAGE(XA, WA)                                                        \
    {                                                                         \
        *(half8*)&As[srow][scol]      = XA[0];                                \
        *(half8*)&As[srow + 64][scol] = XA[1];                                \
        *(half8*)&Bs[srow][scol]      = WA[0];                                \
        *(half8*)&Bs[srow + 64][scol] = WA[1];                                \
    }

#define PCOMP                                                                 \
    {                                                                         \
        half8 af[4], bf[4];                                                   \
        _Pragma("unroll")                                                     \
        for (int mt = 0; mt < 4; mt++)                                        \
            af[mt] = *(const half8*)&As[wm + mt * 16 + lc][quad * 8];         \
        _Pragma("unroll")                                                     \
        for (int nt = 0; nt < 4; nt++)                                        \
            bf[nt] = *(const half8*)&Bs[wn + nt * 16 + lc][quad * 8];         \
        _Pragma("unroll")                                                     \
        for (int mt = 0; mt < 4; mt++)                                        \
            _Pragma("unroll")                                                 \
            for (int nt = 0; nt < 4; nt++)                                    \
                acc[mt][nt] = __builtin_amdgcn_mfma_f32_16x16x32_f16(         \
                    af[mt], bf[nt], acc[mt][nt], 0, 0, 0);                    \
    }

    PISS(0,  xa0, wa0)
    PISS(32, xa1, wa1)

    for (int k0 = 0; k0 < HDIM; k0 += 64) {
        if (k0) __syncthreads();        // prev compute done reading LDS
        PSTAGE(xa0, wa0)
        __syncthreads();
        if (k0 + 64 < HDIM) PISS(k0 + 64, xa0, wa0)
        PCOMP
        __syncthreads();
        PSTAGE(xa1, wa1)
        __syncthreads();
        if (k0 + 96 < HDIM) PISS(k0 + 96, xa1, wa1)
        PCOMP
    }

#pragma unroll
    for (int nt = 0; nt < 4; nt++) {
        const int n = n0 + wn + nt * 16 + lc;          // h*64 + d
        const float bv_ = bias[n];
        const int h = n >> 6, d = n & 63;
#pragma unroll
        for (int mt = 0; mt < 4; mt++) {
#pragma unroll
            for (int r = 0; r < 4; r++) {
                const int m = m0 + wm + mt * 16 + quad * 4 + r;   // b*S + s
                const int b = m >> 11, s = m & (S_LEN - 1);
                const int bh = b * NHEAD + h;
                float y = acc[mt][nt][r] + bv_;
                if (z == 0) y *= LOG2E;                 // exp2-fold for attn
                _Float16 val = (_Float16)y;
                if (z == 2)
                    Y[((size_t)bh * HD + d) * S_LEN + s] = val;          // V^T
                else
                    Y[((size_t)bh * S_LEN + s) * HD + d] = val;          // Q,K
            }
        }
    }
}

// ---------------------------------------------------------------------------
// Projection GEMM, fp32 inputs (FALLBACK when workspace is too small for the
// f16 path).  Identical to the verified R5 kernel (84us).
// ---------------------------------------------------------------------------
__global__ __launch_bounds__(256) void proj_gemm_f32in(
    const float* __restrict__ Xq, const float* __restrict__ Wq, const float* __restrict__ bq,
    const float* __restrict__ Xk, const float* __restrict__ Wk, const float* __restrict__ bk,
    const float* __restrict__ Xv, const float* __restrict__ Wv, const float* __restrict__ bv,
    _Float16* __restrict__ Qb, _Float16* __restrict__ Kb, _Float16* __restrict__ Vtb)
{
    const int l  = blockIdx.x;           // 0..767
    const int x  = l & 7;                // XCD
    const int j  = l >> 3;               // 0..95
    const int mt_ = x * 4 + (j & 3);     // 0..31
    const int nt_ = (j >> 2) & 7;        // 0..7
    const int z   = j >> 5;              // 0..2

    const float* X    = (z == 0) ? Xq : (z == 1) ? Xk : Xv;
    const float* W    = (z == 0) ? Wq : (z == 1) ? Wk : Wv;
    const float* bias = (z == 0) ? bq : (z == 1) ? bk : bv;
    _Float16* Y       = (z == 0) ? Qb : (z == 1) ? Kb : Vtb;

    const int n0 = nt_ * 128;
    const int m0 = mt_ * 128;

    __shared__ __align__(16) _Float16 As[128][40];
    __shared__ __align__(16) _Float16 Bs[128][40];

    const int t    = threadIdx.x;
    const int w    = t >> 6;
    const int lane = t & 63;
    const int quad = lane >> 4;
    const int lc   = lane & 15;
    const int wm   = (w >> 1) * 64;
    const int wn   = (w & 1) * 64;

    const f32x4 fzero = {0.f, 0.f, 0.f, 0.f};
    f32x4 acc[4][4];
#pragma unroll
    for (int i = 0; i < 4; i++)
#pragma unroll
        for (int j2 = 0; j2 < 4; j2++) acc[i][j2] = fzero;

    const int srow = t >> 2;
    const int sc   = t & 3;

    float4 xa0[2][2], wa0[2][2], xa1[2][2], wa1[2][2];

#define PROJ_ISSUE(K0, XA, WA)                                                \
    {                                                                         \
        _Pragma("unroll")                                                     \
        for (int hf = 0; hf < 2; hf++) {                                      \
            const float* gx = X + (size_t)(m0 + srow + hf * 64) * HDIM + (K0) + sc * 8; \
            XA[hf][0] = *(const float4*)gx;                                   \
            XA[hf][1] = *(const float4*)(gx + 4);                             \
            const float* gw = W + (size_t)(n0 + srow + hf * 64) * HDIM + (K0) + sc * 8; \
            WA[hf][0] = *(const float4*)gw;                                   \
            WA[hf][1] = *(const float4*)(gw + 4);                             \
        }                                                                     \
    }

#define PROJ_STAGE(XA, WA)                                                    \
    {                                                                         \
        _Pragma("unroll")                                                     \
        for (int hf = 0; hf < 2; hf++) {                                      \
            int row = srow + hf * 64;                                         \
            *(half8*)&As[row][sc * 8] = pk8(make_float4(XA[hf][0].x, XA[hf][0].y, XA[hf][0].z, XA[hf][0].w), XA[hf][1]); \
            *(half8*)&Bs[row][sc * 8] = pk8(WA[hf][0], WA[hf][1]);            \
        }                                                                     \
    }

    PROJ_ISSUE(0,  xa0, wa0)
    PROJ_ISSUE(32, xa1, wa1)

    for (int k0 = 0; k0 < HDIM; k0 += 64) {
        if (k0) __syncthreads();
        PROJ_STAGE(xa0, wa0)
        __syncthreads();
        if (k0 + 64 < HDIM) PROJ_ISSUE(k0 + 64, xa0, wa0)
        PCOMP
        __syncthreads();
        PROJ_STAGE(xa1, wa1)
        __syncthreads();
        if (k0 + 96 < HDIM) PROJ_ISSUE(k0 + 96, xa1, wa1)
        PCOMP
    }

#pragma unroll
    for (int nt = 0; nt < 4; nt++) {
        const int n = n0 + wn + nt * 16 + lc;
        const float bv_ = bias[n];
        const int h = n >> 6, d = n & 63;
#pragma unroll
        for (int mt = 0; mt < 4; mt++) {
#pragma unroll
            for (int r = 0; r < 4; r++) {
                const int m = m0 + wm + mt * 16 + quad * 4 + r;
                const int b = m >> 11, s = m & (S_LEN - 1);
                const int bh = b * NHEAD + h;
                float y = acc[mt][nt][r] + bv_;
                if (z == 0) y *= LOG2E;
                _Float16 val = (_Float16)y;
                if (z == 2)
                    Y[((size_t)bh * HD + d) * S_LEN + s] = val;
                else
                    Y[((size_t)bh * S_LEN + s) * HD + d] = val;
            }
        }
    }
}

// ---------------------------------------------------------------------------
// Flash attention v4 (unchanged from R4).  Padded [64][72] LDS (immediate
// offsets), bias folded into MFMA C-init, exp2 log2-domain softmax, v_max3
// trees, cvt_pkrtz packed P, defer-max, XCD-aware block swizzle.
// S^T = K.Q^T, O^T = V^T.P^T, 128-row tiles, 4 waves, 2 q-groups/wave.
// ---------------------------------------------------------------------------
__global__ __launch_bounds__(256) void flash_attn_mfma(
    const _Float16* __restrict__ Qb, const _Float16* __restrict__ Kb,
    const _Float16* __restrict__ Vtb, const int* __restrict__ mask,
    float* __restrict__ out)
{
    const int bid = blockIdx.x;                  // 0..511
    const int swz = (bid & 7) * 64 + (bid >> 3);
    const int qt = swz & 15;                     // 16 q-tiles of 128 rows
    const int bh = swz >> 4;                     // 0..31
    const int b  = bh >> 4;
    const int h  = bh & (NHEAD - 1);

    __shared__ __align__(16) _Float16 Ks [64][72];      // [key][d]
    __shared__ __align__(16) _Float16 Vts[64][72];      // [d][key]
    __shared__ __align__(16) _Float16 Ps [4][32][72];   // per-wave P, [q][key]
    __shared__ float biasS[64];                         // mask bias per key

    const int t    = threadIdx.x;
    const int w    = t >> 6;
    const int lane = t & 63;
    const int quad = lane >> 4;
    const int lc   = lane & 15;

    const _Float16* Kbase = Kb  + (size_t)bh * S_LEN * HD;
    const _Float16* Vbase = Vtb + (size_t)bh * HD * S_LEN;
    const int* mbase = mask + b * S_LEN;

    half8 qf[2][2];
#pragma unroll
    for (int qg = 0; qg < 2; qg++) {
        const int qrow = qt * 128 + w * 32 + qg * 16 + lc;
#pragma unroll
        for (int s = 0; s < 2; s++)
            qf[qg][s] = *(const half8*)(Qb + ((size_t)bh * S_LEN + qrow) * HD
                                        + s * 32 + quad * 8);
    }

    f32x4 o[2][4];
    const f32x4 fzero = {0.f, 0.f, 0.f, 0.f};
#pragma unroll
    for (int qg = 0; qg < 2; qg++)
#pragma unroll
        for (int nt = 0; nt < 4; nt++) o[qg][nt] = fzero;
    float mrun[2] = {-3.0e38f, -3.0e38f};
    float lrun[2] = {0.f, 0.f};

    const int rr0 = t >> 3,          cc0 = (t & 7) * 8;
    const int rr1 = (t + 256) >> 3;

    half8 kpre[2], vpre[2];
    int   mpre;
#define ATTN_ISSUE(KT)                                                        \
    {                                                                         \
        kpre[0] = *(const half8*)(Kbase + (size_t)((KT) + rr0) * HD + cc0);   \
        kpre[1] = *(const half8*)(Kbase + (size_t)((KT) + rr1) * HD + cc0);   \
        vpre[0] = *(const half8*)(Vbase + (size_t)rr0 * S_LEN + (KT) + cc0);  \
        vpre[1] = *(const half8*)(Vbase + (size_t)rr1 * S_LEN + (KT) + cc0);  \
        mpre    = mbase[(KT) + (t & 63)];                                     \
    }

    ATTN_ISSUE(0)

    for (int kt = 0; kt < S_LEN; kt += 64) {
        if (kt) __syncthreads();
        *(half8*)&Ks [rr0][cc0] = kpre[0];
        *(half8*)&Ks [rr1][cc0] = kpre[1];
        *(half8*)&Vts[rr0][cc0] = vpre[0];
        *(half8*)&Vts[rr1][cc0] = vpre[1];
        if (t < 64) biasS[t] = mpre ? 0.f : NEGBIAS;
        __syncthreads();

        if (kt + 64 < S_LEN) ATTN_ISSUE(kt + 64)

        f32x4 scf[2][4];
#pragma unroll
        for (int tt = 0; tt < 4; tt++) {
            float4 b4 = *(const float4*)&biasS[tt * 16 + quad * 4];
            f32x4 cini = {b4.x, b4.y, b4.z, b4.w};
            scf[0][tt] = cini;
            scf[1][tt] = cini;
        }
#pragma unroll
        for (int s = 0; s < 2; s++) {
#pragma unroll
            for (int tt = 0; tt < 4; tt++) {
                half8 kf = *(const half8*)&Ks[tt * 16 + lc][s * 32 + quad * 8];
                scf[0][tt] = __builtin_amdgcn_mfma_f32_16x16x32_f16(kf, qf[0][s], scf[0][tt], 0, 0, 0);
                scf[1][tt] = __builtin_amdgcn_mfma_f32_16x16x32_f16(kf, qf[1][s], scf[1][tt], 0, 0, 0);
            }
        }

#pragma unroll
        for (int qg = 0; qg < 2; qg++) {
            const f32x4 a0 = scf[qg][0], a1 = scf[qg][1],
                        a2 = scf[qg][2], a3 = scf[qg][3];
            float m0 = max3f(a0[0], a0[1], a0[2]);
            float m1 = max3f(a0[3], a1[0], a1[1]);
            float m2 = max3f(a1[2], a1[3], a2[0]);
            float m3 = max3f(a2[1], a2[2], a2[3]);
            float m4 = max3f(a3[0], a3[1], a3[2]);
            float mx = fmaxf(max3f(m0, m1, m2), max3f(m3, m4, a3[3]));
            mx = fmaxf(mx, __shfl_xor(mx, 16));
            mx = fmaxf(mx, __shfl_xor(mx, 32));

            if (!__all(mx <= mrun[qg] + 8.f)) {
                float mn = fmaxf(mrun[qg], mx);
                float al = __builtin_amdgcn_exp2f(mrun[qg] - mn);
                lrun[qg] *= al;
#pragma unroll
                for (int nt = 0; nt < 4; nt++) {
                    o[qg][nt][0] *= al; o[qg][nt][1] *= al;
                    o[qg][nt][2] *= al; o[qg][nt][3] *= al;
                }
                mrun[qg] = mn;
            }

            const float mr = mrun[qg];
            float ps[4][4];
#pragma unroll
            for (int tt = 0; tt < 4; tt++)
#pragma unroll
                for (int r = 0; r < 4; r++) {
                    float p = __builtin_amdgcn_exp2f(scf[qg][tt][r] - mr);
                    ps[tt][r] = p;
                }
            float s0 = (ps[0][0] + ps[0][1]) + (ps[0][2] + ps[0][3]);
            float s1 = (ps[1][0] + ps[1][1]) + (ps[1][2] + ps[1][3]);
            float s2 = (ps[2][0] + ps[2][1]) + (ps[2][2] + ps[2][3]);
            float s3 = (ps[3][0] + ps[3][1]) + (ps[3][2] + ps[3][3]);
            float ls = (s0 + s1) + (s2 + s3);
            ls += __shfl_xor(ls, 16);
            ls += __shfl_xor(ls, 32);
            lrun[qg] += ls;

#pragma unroll
            for (int tt = 0; tt < 4; tt++) {
                fp16x2 p01 = __builtin_amdgcn_cvt_pkrtz(ps[tt][0], ps[tt][1]);
                fp16x2 p23 = __builtin_amdgcn_cvt_pkrtz(ps[tt][2], ps[tt][3]);
                fp16x4 pk4 = __builtin_shufflevector(p01, p23, 0, 1, 2, 3);
                *(half4*)&Ps[w][qg * 16 + lc][tt * 16 + quad * 4] =
                    __builtin_bit_cast(half4, pk4);
            }
        }

#pragma unroll
        for (int s = 0; s < 2; s++) {
            half8 pf0 = *(const half8*)&Ps[w][lc]     [s * 32 + quad * 8];
            half8 pf1 = *(const half8*)&Ps[w][16 + lc][s * 32 + quad * 8];
#pragma unroll
            for (int nt = 0; nt < 4; nt++) {
                half8 vf = *(const half8*)&Vts[nt * 16 + lc][s * 32 + quad * 8];
                o[0][nt] = __builtin_amdgcn_mfma_f32_16x16x32_f16(vf, pf0, o[0][nt], 0, 0, 0);
                o[1][nt] = __builtin_amdgcn_mfma_f32_16x16x32_f16(vf, pf1, o[1][nt], 0, 0, 0);
            }
        }
    }

#pragma unroll
    for (int qg = 0; qg < 2; qg++) {
        const int qrow = qt * 128 + w * 32 + qg * 16 + lc;
        const float inv = 1.f / lrun[qg];
        const size_t rowb = ((size_t)b * S_LEN + qrow) * HDIM + h * HD;
#pragma unroll
        for (int nt = 0; nt < 4; nt++) {
            float4 v;
            v.x = o[qg][nt][0] * inv; v.y = o[qg][nt][1] * inv;
            v.z = o[qg][nt][2] * inv; v.w = o[qg][nt][3] * inv;
            *(float4*)&out[rowb + nt * 16 + quad * 4] = v;
        }
    }
}

// ---------------------------------------------------------------------------
extern "C" void kernel_launch(void* const* d_in, const int* in_sizes, int n_in,
                              void* d_out, int out_size, void* d_ws, size_t ws_size,
                              hipStream_t stream) {
    const float* query = (const float*)d_in[0];
    const float* key   = (const float*)d_in[1];
    const float* value = (const float*)d_in[2];
    const int*   mask  = (const int*)  d_in[3];
    const float* Wq    = (const float*)d_in[4];
    const float* bq    = (const float*)d_in[5];
    const float* Wk    = (const float*)d_in[6];
    const float* bk    = (const float*)d_in[7];
    const float* Wv    = (const float*)d_in[8];
    const float* bv    = (const float*)d_in[9];
    float* out = (float*)d_out;

    const size_t nElem = (size_t)BATCH * S_LEN * HDIM;          // 4M
    const size_t wElem = (size_t)HDIM * HDIM;                   // 1M
    if (ws_size < 3 * nElem * sizeof(_Float16)) return;         // 24 MB min
    _Float16* Qb  = (_Float16*)d_ws;
    _Float16* Kb  = Qb + nElem;
    _Float16* Vtb = Kb + nElem;

    // f16-input path scratch: Xf_q/Xf_k live in d_out (write-only until
    // flash, which fully overwrites it); Xf_v + W's extend the workspace.
    const size_t needWs  = (3 * nElem + nElem + 3 * wElem) * sizeof(_Float16);
    const bool   f16path = (ws_size >= needWs) &&
                           ((size_t)out_size >= 2 * nElem * sizeof(_Float16));

    if (f16path) {
        _Float16* Xfq = (_Float16*)d_out;
        _Float16* Xfk = Xfq + nElem;
        _Float16* Xfv = Vtb + nElem;
        _Float16* Wfq = Xfv + nElem;
        _Float16* Wfk = Wfq + wElem;
        _Float16* Wfv = Wfk + wElem;

        cvt_f32_f16<<<7680, 256, 0, stream>>>(query, key, value, Wq, Wk, Wv,
                                              Xfq, Xfk, Xfv, Wfq, Wfk, Wfv);
        proj_gemm_f16in<<<768, 256, 0, stream>>>(Xfq, Wfq, bq, Xfk, Wfk, bk,
                                                 Xfv, Wfv, bv, Qb, Kb, Vtb);
    } else {
        proj_gemm_f32in<<<768, 256, 0, stream>>>(query, Wq, bq, key, Wk, bk,
                                                 value, Wv, bv, Qb, Kb, Vtb);
    }

    flash_attn_mfma<<<BATCH * NHEAD * (S_LEN / 128), 256, 0, stream>>>(
        Qb, Kb, Vtb, mask, out);
}